// Round 6
// baseline (19.420 us; speedup 1.0000x reference)
//
#include <hip/hip_runtime.h>
#include <hip/hip_bf16.h>

#define NCLASS 10
#define B_BYTES 81920   // B: [10][4096] bf16, XOR-swizzled; reused as reduce scratch

typedef __bf16 bf16x8 __attribute__((ext_vector_type(8)));
typedef __bf16 bf16x2 __attribute__((ext_vector_type(2)));
typedef float  f32x4  __attribute__((ext_vector_type(4)));
typedef float  f32x2  __attribute__((ext_vector_type(2)));

__device__ __forceinline__ unsigned pack2(float lo, float hi) {
    bf16x2 p = {(__bf16)lo, (__bf16)hi};        // v_cvt_pk_bf16_f32
    return __builtin_bit_cast(unsigned, p);
}

__device__ __forceinline__ bf16x8 mk_a(const f32x2* t8v, float base) {
    bf16x8 a;
    #pragma unroll
    for (int i = 0; i < 4; ++i) {
        f32x2 p = t8v[i] * base;                // v_pk_mul_f32
        a[2 * i]     = (__bf16)p[0];
        a[2 * i + 1] = (__bf16)p[1];
    }
    return a;
}

// softmax for one row -> derived per-(row,kg) A-gen params.
// k digits: l5=j&3, l4=2*(kg&1)+(j>>2), l3=2*parity+(kg>>1), l2=s2&3,
//           l1=(s2>>2)|((kc&1)<<1), l0=kc>>1
__device__ __forceinline__ void row_params(
    const float xv[6], const float off1[6], const float off2[6], const float off3[6],
    float sc, int kgl, int kgh, int l0, int l1hi,
    float& b01a, float& b01b, f32x4& b2v, float& b3e, float& b3o, f32x2 t8v[4])
{
    float bins[6][4];
    #pragma unroll
    for (int f = 0; f < 6; ++f) {
        float h0 = xv[f] * sc;
        float h1 = fmaf(xv[f], 2.f * sc, off1[f]);
        float h2 = fmaf(xv[f], 3.f * sc, off2[f]);
        float h3 = fmaf(xv[f], 4.f * sc, off3[f]);
        float m = fmaxf(fmaxf(h0, h1), fmaxf(h2, h3));
        float e0 = exp2f(h0 - m), e1 = exp2f(h1 - m);
        float e2 = exp2f(h2 - m), e3 = exp2f(h3 - m);
        float rs = 1.f / (e0 + e1 + e2 + e3);
        bins[f][0] = e0 * rs; bins[f][1] = e1 * rs;
        bins[f][2] = e2 * rs; bins[f][3] = e3 * rs;
    }
    float b0s = bins[0][l0];
    b01a = b0s * bins[1][l1hi];
    b01b = b0s * bins[1][l1hi + 1];
    b2v = *(f32x4*)&bins[2][0];
    b3e = bins[3][kgh];
    b3o = bins[3][2 + kgh];
    float b4a = bins[4][kgl * 2 + 0], b4b = bins[4][kgl * 2 + 1];
    t8v[0] = (f32x2){b4a * bins[5][0], b4a * bins[5][1]};
    t8v[1] = (f32x2){b4a * bins[5][2], b4a * bins[5][3]};
    t8v[2] = (f32x2){b4b * bins[5][0], b4b * bins[5][1]};
    t8v[3] = (f32x2){b4b * bins[5][2], b4b * bins[5][3]};
}

__launch_bounds__(1024, 4)
__global__ void dndt_mfma(const float* __restrict__ x,
                          const float* __restrict__ cuts,
                          const float* __restrict__ ls,
                          const float* __restrict__ temperature,
                          float* __restrict__ out)
{
    __shared__ __attribute__((aligned(16))) char LS[B_BYTES];
    const int tid = threadIdx.x;
    const int w = tid >> 6, lane = tid & 63;
    const int r = lane & 15, kg = lane >> 4;
    const int kc = w & 7;          // K-chunk (8-way split, 512 k each)
    const int rtg = w >> 3;        // row-tile group: tiles rtg*2, rtg*2+1

    // ---- issue x loads early (rows rl0 and rl0+16) ----
    const int rl0 = rtg * 32 + r;
    const int grow0 = (blockIdx.x << 6) + rl0;
    const float2* x2 = (const float2*)x;
    float2 xa0 = x2[grow0 * 3 + 0], xa1 = x2[grow0 * 3 + 1], xa2 = x2[grow0 * 3 + 2];
    float2 xb0 = x2[(grow0 + 16) * 3 + 0], xb1 = x2[(grow0 + 16) * 3 + 1],
           xb2 = x2[(grow0 + 16) * 3 + 2];

    // ---- issue staging loads: thread owns leaf-quad jq (4 leaves = 40 floats) ----
    const float4* ls4 = (const float4*)ls;
    float4 g[10];
    #pragma unroll
    for (int i = 0; i < 10; ++i) g[i] = ls4[10 * tid + i];

    // ---- cuts -> sorted -> scaled offsets (uniform) ----
    const float sc = 1.44269504088896f / temperature[0];   // log2(e)/t
    float off1[6], off2[6], off3[6];
    #pragma unroll
    for (int f = 0; f < 6; ++f) {
        float c0 = cuts[f * 3 + 0], c1 = cuts[f * 3 + 1], cv = cuts[f * 3 + 2];
        float lo01 = fminf(c0, c1), hi01 = fmaxf(c0, c1);
        float s2 = fmaxf(hi01, cv), mh = fminf(hi01, cv);
        float s0 = fminf(lo01, mh), s1 = fmaxf(lo01, mh);
        off1[f] = -s0 * sc;
        off2[f] = (-s0 - s1) * sc;
        off3[f] = (-s0 - s1 - s2) * sc;
    }

    // ---- per-lane softmax + derived params for the wave's 2 rows ----
    const int kgl = kg & 1, kgh = kg >> 1;
    const int l0 = kc >> 1, l1hi = (kc & 1) << 1;
    float b01a0, b01b0, b3e0, b3o0, b01a1, b01b1, b3e1, b3o1;
    f32x4 b2v0, b2v1;
    f32x2 t80[4], t81[4];
    {
        float xv0[6] = {xa0.x, xa0.y, xa1.x, xa1.y, xa2.x, xa2.y};
        row_params(xv0, off1, off2, off3, sc, kgl, kgh, l0, l1hi,
                   b01a0, b01b0, b2v0, b3e0, b3o0, t80);
        float xv1[6] = {xb0.x, xb0.y, xb1.x, xb1.y, xb2.x, xb2.y};
        row_params(xv1, off1, off2, off3, sc, kgl, kgh, l0, l1hi,
                   b01a1, b01b1, b2v1, b3e1, b3o1, t81);
    }

    // ---- pack leaf quad into swizzled LDS: (n,k) at byte n*8192 + ((2k)^((n&7)<<4)) ----
    {
        float v[40];
        #pragma unroll
        for (int i = 0; i < 10; ++i) {
            v[4 * i] = g[i].x; v[4 * i + 1] = g[i].y;
            v[4 * i + 2] = g[i].z; v[4 * i + 3] = g[i].w;
        }
        #pragma unroll
        for (int n = 0; n < NCLASS; ++n) {
            uint2 dw = { pack2(v[n], v[10 + n]), pack2(v[20 + n], v[30 + n]) };
            unsigned addr = ((unsigned)n << 13) +
                            (((unsigned)(tid << 3)) ^ (((unsigned)(n & 7)) << 4));
            *(uint2*)(LS + addr) = dw;
        }
    }

    __syncthreads();

    // ---- B-read bases: byte = n<<13 + kc*1024 + s2*128 + [(kg<<4 | e<<6) ^ (n&7)<<4] ----
    const int n_eff = (r < NCLASS) ? r : 9;
    const unsigned base0 = ((unsigned)n_eff << 13) + ((unsigned)kc << 10) +
                           ((((unsigned)kg) << 4) ^ ((((unsigned)n_eff) & 3u) << 4));
    const unsigned c6 = (((unsigned)n_eff) >> 2) & 1u;
    const char* pe = LS + base0 + (c6 << 6);          // even steps
    const char* po = LS + base0 + ((1u - c6) << 6);   // odd steps

    // ---- K-loop: 16 B-reads, 32 MFMAs (2 row-tiles share each B fragment) ----
    f32x4 acc0 = {0.f, 0.f, 0.f, 0.f}, acc1 = {0.f, 0.f, 0.f, 0.f};
    #pragma unroll
    for (int s2 = 0; s2 < 8; ++s2) {
        bf16x8 Be = *(const bf16x8*)(pe + s2 * 128);
        bf16x8 Bo = *(const bf16x8*)(po + s2 * 128);
        float m0 = b2v0[s2 & 3] * ((s2 >> 2) ? b01b0 : b01a0);
        float m1 = b2v1[s2 & 3] * ((s2 >> 2) ? b01b1 : b01a1);
        acc0 = __builtin_amdgcn_mfma_f32_16x16x32_bf16(mk_a(t80, m0 * b3e0), Be, acc0, 0, 0, 0);
        acc1 = __builtin_amdgcn_mfma_f32_16x16x32_bf16(mk_a(t81, m1 * b3e1), Be, acc1, 0, 0, 0);
        acc0 = __builtin_amdgcn_mfma_f32_16x16x32_bf16(mk_a(t80, m0 * b3o0), Bo, acc0, 0, 0, 0);
        acc1 = __builtin_amdgcn_mfma_f32_16x16x32_bf16(mk_a(t81, m1 * b3o1), Bo, acc1, 0, 0, 0);
    }

    // ---- reduce 8 K-chunk partials per row-tile through LDS (reuse B region) ----
    // slot(rt,kc) = (rt>>1)*16 + kc*2 + (rt&1); wave w writes slots w*2 (rt=rtg*2), w*2+1
    __syncthreads();
    f32x4* red = (f32x4*)LS;
    red[(w * 2 + 0) * 64 + lane] = acc0;
    red[(w * 2 + 1) * 64 + lane] = acc1;
    __syncthreads();
    if (w < 4) {
        const int rt = w;
        const int sbase = (rt >> 1) * 16 + (rt & 1);
        f32x4 tot = red[sbase * 64 + lane];
        #pragma unroll
        for (int k8 = 1; k8 < 8; ++k8) tot += red[(sbase + 2 * k8) * 64 + lane];
        if (r < NCLASS) {   // D: col = r = class, row = kg*4 + q
            #pragma unroll
            for (int q = 0; q < 4; ++q) {
                int grow = (blockIdx.x << 6) + rt * 16 + kg * 4 + q;
                out[(size_t)grow * NCLASS + r] = tot[q];
            }
        }
    }
}

extern "C" void kernel_launch(void* const* d_in, const int* in_sizes, int n_in,
                              void* d_out, int out_size, void* d_ws, size_t ws_size,
                              hipStream_t stream) {
    const float* x           = (const float*)d_in[0];
    const float* cuts        = (const float*)d_in[1];
    const float* leaf_score  = (const float*)d_in[2];
    const float* temperature = (const float*)d_in[3];
    float* out = (float*)d_out;
    // 16384 rows / 64 rows-per-block = 256 blocks (1 per CU), 16 waves each
    dndt_mfma<<<256, 1024, 0, stream>>>(x, cuts, leaf_score, temperature, out);
}

// Round 7
// 12.188 us; speedup vs baseline: 1.5933x; 1.5933x over previous
//
#include <hip/hip_runtime.h>
#include <hip/hip_bf16.h>

#define NCLASS 10
#define B_BYTES 81920                  // B: [10][4096] bf16, XOR-swizzled
#define BINS_OFF 81920                 // bins region after B
#define BINS_STRIDE 28                 // dwords per row (24 used, padded vs banks)
#define LDS_BYTES (B_BYTES + 64 * BINS_STRIDE * 4)   // 89088 B -> 1 block/CU, 16 waves

typedef __bf16 bf16x8 __attribute__((ext_vector_type(8)));
typedef __bf16 bf16x2 __attribute__((ext_vector_type(2)));
typedef float  f32x4  __attribute__((ext_vector_type(4)));
typedef float  f32x2  __attribute__((ext_vector_type(2)));

__device__ __forceinline__ unsigned pack2(float lo, float hi) {
    bf16x2 p = {(__bf16)lo, (__bf16)hi};        // v_cvt_pk_bf16_f32
    return __builtin_bit_cast(unsigned, p);
}

__device__ __forceinline__ bf16x8 mk_a(const f32x2* t8v, float base) {
    bf16x8 a;
    #pragma unroll
    for (int i = 0; i < 4; ++i) {
        f32x2 p = t8v[i] * base;                // v_pk_mul_f32
        a[2 * i]     = (__bf16)p[0];            // pairs -> v_cvt_pk_bf16_f32
        a[2 * i + 1] = (__bf16)p[1];
    }
    return a;
}

__launch_bounds__(1024, 4)
__global__ void dndt_mfma(const float* __restrict__ x,
                          const float* __restrict__ cuts,
                          const float* __restrict__ ls,
                          const float* __restrict__ temperature,
                          float* __restrict__ out)
{
    __shared__ __attribute__((aligned(16))) char LS[LDS_BYTES];
    const int tid = threadIdx.x;

    // ---- in-kernel pack: leaf_score [4096][10] f32 -> LDS [10][4096] bf16 swizzled ----
    // element (n,k) at byte n*8192 + ((2k) ^ ((n&7)<<4)); pair (2j,2j+1) shares a dword.
    {
        const float4* ls4 = (const float4*)ls;   // 10240 float4
        #pragma unroll
        for (int pp = 0; pp < 2; ++pp) {
            const int j = pp * 1024 + tid;       // leaf pair 0..2047
            float4 f0 = ls4[5 * j + 0];
            float4 f1 = ls4[5 * j + 1];
            float4 f2 = ls4[5 * j + 2];
            float4 f3 = ls4[5 * j + 3];
            float4 f4 = ls4[5 * j + 4];
            float k0[10] = {f0.x, f0.y, f0.z, f0.w, f1.x, f1.y, f1.z, f1.w, f2.x, f2.y};
            float k1[10] = {f2.z, f2.w, f3.x, f3.y, f3.z, f3.w, f4.x, f4.y, f4.z, f4.w};
            #pragma unroll
            for (int n = 0; n < NCLASS; ++n) {
                unsigned addr = ((unsigned)n << 13) +
                                (((unsigned)(j << 2)) ^ (((unsigned)(n & 7)) << 4));
                *(unsigned*)(LS + addr) = pack2(k0[n], k1[n]);
            }
        }
    }

    // ---- block-shared soft bins: 64 rows x 6 feats, one softmax per thread ----
    float* BINS = (float*)(LS + BINS_OFF);       // [64][BINS_STRIDE] f32
    const float sc = 1.44269504088896f / temperature[0];   // log2(e)/t
    if (tid < 512) {
        const int rl = tid >> 3, f = tid & 7;
        if (f < 6) {
            const int grow = (blockIdx.x << 6) + rl;
            float xv = x[grow * 6 + f];
            float c0 = cuts[f * 3 + 0], c1 = cuts[f * 3 + 1], cv = cuts[f * 3 + 2];
            float lo01 = fminf(c0, c1), hi01 = fmaxf(c0, c1);
            float s2 = fmaxf(hi01, cv), mh = fminf(hi01, cv);
            float s0 = fminf(lo01, mh), s1 = fmaxf(lo01, mh);
            float h0 = xv * sc;
            float h1 = fmaf(xv, 2.f * sc, -s0 * sc);
            float h2 = fmaf(xv, 3.f * sc, (-s0 - s1) * sc);
            float h3 = fmaf(xv, 4.f * sc, (-s0 - s1 - s2) * sc);
            float m = fmaxf(fmaxf(h0, h1), fmaxf(h2, h3));
            float e0 = exp2f(h0 - m), e1 = exp2f(h1 - m);
            float e2 = exp2f(h2 - m), e3 = exp2f(h3 - m);
            float rs = 1.f / (e0 + e1 + e2 + e3);
            f32x4 b = {e0 * rs, e1 * rs, e2 * rs, e3 * rs};
            *(f32x4*)&BINS[rl * BINS_STRIDE + f * 4] = b;
        }
    }

    __syncthreads();

    // ---- per-thread geometry: 8-way K-split x 2 row-tiles per wave ----
    const int w = tid >> 6, lane = tid & 63;
    const int r  = lane & 15;            // A-row within tile AND B/D column
    const int kg = lane >> 4;            // k-group
    const int kc = w & 7;                // K-chunk (512 k's each): l0=kc>>1, l1 hi bit=kc&1
    const int rtg = w >> 3;              // tiles rtg*2, rtg*2+1 (local rows rl0, rl0+16)
    const int rl0 = rtg * 32 + r;

    const int kgl = kg & 1, kgh = kg >> 1;
    const int l0 = kc >> 1, l1hi = (kc & 1) << 1;

    // per-row derived A-gen params, bins read from LDS (no softmax duplication)
    float b01a0, b01b0, b3e0, b3o0, b01a1, b01b1, b3e1, b3o1;
    f32x4 b2v0, b2v1;
    f32x2 t80[4], t81[4];
    #pragma unroll
    for (int rr = 0; rr < 2; ++rr) {
        const float* BR = &BINS[(rl0 + rr * 16) * BINS_STRIDE];
        f32x4 b0v = *(const f32x4*)&BR[0];
        f32x4 b1v = *(const f32x4*)&BR[4];
        f32x4 b2v = *(const f32x4*)&BR[8];
        f32x4 b3v = *(const f32x4*)&BR[12];
        f32x4 b4v = *(const f32x4*)&BR[16];
        f32x4 b5v = *(const f32x4*)&BR[20];
        float b0s = b0v[l0];
        float ba = b0s * b1v[l1hi], bb = b0s * b1v[l1hi + 1];
        float be = b3v[kgh], bo = b3v[2 + kgh];
        float b4a = b4v[kgl * 2 + 0], b4b = b4v[kgl * 2 + 1];
        f32x2 t0 = {b4a * b5v[0], b4a * b5v[1]};
        f32x2 t1 = {b4a * b5v[2], b4a * b5v[3]};
        f32x2 t2 = {b4b * b5v[0], b4b * b5v[1]};
        f32x2 t3 = {b4b * b5v[2], b4b * b5v[3]};
        if (rr == 0) { b01a0 = ba; b01b0 = bb; b2v0 = b2v; b3e0 = be; b3o0 = bo;
                       t80[0] = t0; t80[1] = t1; t80[2] = t2; t80[3] = t3; }
        else         { b01a1 = ba; b01b1 = bb; b2v1 = b2v; b3e1 = be; b3o1 = bo;
                       t81[0] = t0; t81[1] = t1; t81[2] = t2; t81[3] = t3; }
    }

    // ---- B-read bases: byte = n<<13 + kc<<10 + s2*128 + [(kg<<4 | e<<6) ^ (n&7)<<4] ----
    const int n_eff = (r < NCLASS) ? r : 9;
    const unsigned base0 = ((unsigned)n_eff << 13) + ((unsigned)kc << 10) +
                           ((((unsigned)kg) << 4) ^ ((((unsigned)n_eff) & 3u) << 4));
    const unsigned c6 = (((unsigned)n_eff) >> 2) & 1u;
    const char* pe = LS + base0 + (c6 << 6);          // even steps
    const char* po = LS + base0 + ((1u - c6) << 6);   // odd steps

    // ---- K-loop: 16 B-reads, 32 MFMAs (2 row-tiles share each B fragment) ----
    f32x4 acc0 = {0.f, 0.f, 0.f, 0.f}, acc1 = {0.f, 0.f, 0.f, 0.f};
    #pragma unroll
    for (int s2 = 0; s2 < 8; ++s2) {
        bf16x8 Be = *(const bf16x8*)(pe + s2 * 128);
        bf16x8 Bo = *(const bf16x8*)(po + s2 * 128);
        float m0 = b2v0[s2 & 3] * ((s2 >> 2) ? b01b0 : b01a0);
        float m1 = b2v1[s2 & 3] * ((s2 >> 2) ? b01b1 : b01a1);
        acc0 = __builtin_amdgcn_mfma_f32_16x16x32_bf16(mk_a(t80, m0 * b3e0), Be, acc0, 0, 0, 0);
        acc1 = __builtin_amdgcn_mfma_f32_16x16x32_bf16(mk_a(t81, m1 * b3e1), Be, acc1, 0, 0, 0);
        acc0 = __builtin_amdgcn_mfma_f32_16x16x32_bf16(mk_a(t80, m0 * b3o0), Bo, acc0, 0, 0, 0);
        acc1 = __builtin_amdgcn_mfma_f32_16x16x32_bf16(mk_a(t81, m1 * b3o1), Bo, acc1, 0, 0, 0);
    }

    // ---- reduce 8 K-chunk partials per row-tile through LDS (reuse B region) ----
    // writer: wave w -> slots w*2+e (e = tile within pair); slot = rtg*16 + kc*2 + e
    // reader: tile rt -> sbase = (rt>>1)*16 + (rt&1), partial k8 at sbase + 2*k8
    __syncthreads();
    f32x4* red = (f32x4*)LS;
    red[(w * 2 + 0) * 64 + lane] = acc0;
    red[(w * 2 + 1) * 64 + lane] = acc1;
    __syncthreads();
    if (w < 4) {
        const int rt = w;
        const int sbase = (rt >> 1) * 16 + (rt & 1);
        f32x4 tot = red[sbase * 64 + lane];
        #pragma unroll
        for (int k8 = 1; k8 < 8; ++k8) tot += red[(sbase + 2 * k8) * 64 + lane];
        if (r < NCLASS) {   // D: col = r = class, row = kg*4 + q
            #pragma unroll
            for (int q = 0; q < 4; ++q) {
                int grow = (blockIdx.x << 6) + rt * 16 + kg * 4 + q;
                out[(size_t)grow * NCLASS + r] = tot[q];
            }
        }
    }
}

extern "C" void kernel_launch(void* const* d_in, const int* in_sizes, int n_in,
                              void* d_out, int out_size, void* d_ws, size_t ws_size,
                              hipStream_t stream) {
    const float* x           = (const float*)d_in[0];
    const float* cuts        = (const float*)d_in[1];
    const float* leaf_score  = (const float*)d_in[2];
    const float* temperature = (const float*)d_in[3];
    float* out = (float*)d_out;
    // 16384 rows / 64 rows-per-block = 256 blocks (1 per CU), 16 waves each
    dndt_mfma<<<256, 1024, 0, stream>>>(x, cuts, leaf_score, temperature, out);
}